// Round 11
// baseline (239.358 us; speedup 1.0000x reference)
//
#include <hip/hip_runtime.h>
#include <math.h>

// DVGO volume-rendering forward, round 20.
// r19 post-mortem: -14us regression = the 1-block serial bucket_rays kernel;
// locality gain was nil (full-box rays defeat octant bucketing). Axis closed,
// bucketing reverted. Remaining signal: OccupancyPercent ~26-30% in EVERY
// round = tail-dominated execution (stragglers = full-box on-rays run on an
// emptying machine). The only lever that measurably worked was splitting each
// ray across waves (r17: 4 waves/ray, 9->3 serial chunks, 56.5->49.3).
// r20 takes the last notch: 8 waves/ray (512-thread block). Wave w owns
// chunk w; wave 0 also owns chunk 8. Straggler critical path 3 -> 2 chunks.
// Same proven scan / LDS chunk-product prefix / interleaved-store structure.
// Predicted: dvgo ~49 -> 43-46us, total -> ~212-215; FETCH/WRITE unchanged.
// If total >= r17 (~218): tail lever exhausted, revert to r17 and stop.

namespace {
constexpr int   kR   = 8192;
constexpr int   kS   = 558;
constexpr int   kNC  = (kS + 63) / 64;            // 9 chunks
constexpr int   kWPR = 8;                         // waves per ray
constexpr int   kG   = 160;
constexpr int   kG3  = kG * kG * kG;
constexpr float kNear = 0.05f;
constexpr float kFar  = 6.0f;
constexpr float kStepWorld = 0.5f * (2.0f / 160.0f);  // STEPSIZE * VOXEL_SIZE
constexpr float kActShift = -13.815509557963774f;     // log(1/(1-1e-6)-1)
constexpr float kLog2e = 1.4426950408889634f;
// brick layout: 2x2x4 voxels, 16 records x 4B = 64B = one cache line
constexpr int   kBX = 80, kBY = 80, kBZ = 40;
constexpr int   kNB = kBX * kBY * kBZ;            // 256000 bricks
constexpr int   kGridWords = kNB * 16;            // 16.4 MB per grid
constexpr int   kXS = kBY * kBZ * 16;             // x-brick stride in words
constexpr int   kYS = kBZ * 16;                   // y-brick stride in words
}

typedef unsigned int nuint4 __attribute__((ext_vector_type(4)));
typedef float        nfloat2 __attribute__((ext_vector_type(2)));
typedef float        nfloat4 __attribute__((ext_vector_type(4)));

__device__ __forceinline__ float fexp(float x) {   // e^x
  return __builtin_amdgcn_exp2f(x * kLog2e);
}
__device__ __forceinline__ float sigmoidf_(float x) {
  return __builtin_amdgcn_rcpf(1.0f + fexp(-x));
}

// ---- repack: planar 7-channel f32 -> two bricked fp8 grids (r12, proven) ----
__global__ __launch_bounds__(256) void repack_grids(
    const float* __restrict__ density,
    const float* __restrict__ off_c,
    const float* __restrict__ emo_c,
    unsigned* __restrict__ gridA,    // [kNB*16] dens|off0|off1|off2
    unsigned* __restrict__ gridB)    // [kNB*16] emo0|emo1|emo2|0
{
  const int t   = blockIdx.x * blockDim.x + threadIdx.x;
  const int bid = t >> 2;
  const int q   = t & 3;
  if (bid >= kNB) return;
  const int bz = bid % kBZ;
  const int u  = bid / kBZ;
  const int by = u % kBY;
  const int bx = u / kBY;
  const int x  = bx * 2 + (q >> 1);
  const int y  = by * 2 + (q & 1);
  const int z0 = bz * 4;
  const int vbase = (x * kG + y) * kG + z0;

  const nfloat4 d  = __builtin_nontemporal_load((const nfloat4*)(density + vbase));
  const nfloat4 f0 = __builtin_nontemporal_load((const nfloat4*)(off_c + vbase));
  const nfloat4 f1 = __builtin_nontemporal_load((const nfloat4*)(off_c + vbase + kG3));
  const nfloat4 f2 = __builtin_nontemporal_load((const nfloat4*)(off_c + vbase + 2 * kG3));
  const nfloat4 e0 = __builtin_nontemporal_load((const nfloat4*)(emo_c + vbase));
  const nfloat4 e1 = __builtin_nontemporal_load((const nfloat4*)(emo_c + vbase + kG3));
  const nfloat4 e2 = __builtin_nontemporal_load((const nfloat4*)(emo_c + vbase + 2 * kG3));

  nuint4 va, vb;
  #pragma unroll
  for (int lz = 0; lz < 4; ++lz) {
    int qa = __builtin_amdgcn_cvt_pk_fp8_f32(d[lz],  f0[lz], 0,  false);
    qa     = __builtin_amdgcn_cvt_pk_fp8_f32(f1[lz], f2[lz], qa, true);
    int qb = __builtin_amdgcn_cvt_pk_fp8_f32(e0[lz], e1[lz], 0,  false);
    qb     = __builtin_amdgcn_cvt_pk_fp8_f32(e2[lz], 0.0f,   qb, true);
    va[lz] = (unsigned)qa;
    vb[lz] = (unsigned)qb;
  }
  const size_t woff = (size_t)bid * 16 + q * 4;
  __builtin_nontemporal_store(va, (nuint4*)(gridA + woff));
  __builtin_nontemporal_store(vb, (nuint4*)(gridB + woff));
}

// ---- main: one block (8 waves) per ray; wave w owns chunk w (+ chunk 8 for w=0) ----
__global__ __launch_bounds__(512) void dvgo_fwd(
    const float* __restrict__ rays_o,
    const float* __restrict__ rays_d,
    const float* __restrict__ jitter,
    const int*   __restrict__ em_modes,
    const unsigned* __restrict__ gridA,
    const unsigned* __restrict__ gridB,
    float* __restrict__ out)
{
  const int ray  = blockIdx.x;
  const int wv   = (threadIdx.x >> 6) & 7;
  const int lane = threadIdx.x & 63;

  __shared__ float s_prod[kNC];
  __shared__ float s_acc[kWPR][3];

  const float ox = rays_o[ray * 3 + 0];
  const float oy = rays_o[ray * 3 + 1];
  const float oz = rays_o[ray * 3 + 2];
  const float dx = rays_d[ray * 3 + 0];
  const float dy = rays_d[ray * 3 + 1];
  const float dz = rays_d[ray * 3 + 2];
  const float jit = jitter[ray];
  const bool  on  = (em_modes[ray] == 1);

  const float vx = (dx == 0.0f) ? 1e-6f : dx;
  const float vy = (dy == 0.0f) ? 1e-6f : dy;
  const float vz = (dz == 0.0f) ? 1e-6f : dz;
  const float ivx = __builtin_amdgcn_rcpf(vx);
  const float ivy = __builtin_amdgcn_rcpf(vy);
  const float ivz = __builtin_amdgcn_rcpf(vz);
  const float rax = ( 1.0f - ox) * ivx, rbx = (-1.0f - ox) * ivx;
  const float ray_a = ( 1.0f - oy) * ivy, rby = (-1.0f - oy) * ivy;
  const float raz = ( 1.0f - oz) * ivz, rbz = (-1.0f - oz) * ivz;
  float tmin = fmaxf(fmaxf(fminf(rax, rbx), fminf(ray_a, rby)), fminf(raz, rbz));
  float tmax = fminf(fminf(fmaxf(rax, rbx), fmaxf(ray_a, rby)), fmaxf(raz, rbz));
  tmin = fminf(fmaxf(tmin, kNear), kFar);
  tmax = fminf(fmaxf(tmax, kNear), kFar);
  const bool  ray_out = (tmax <= tmin);
  const float stepc = kStepWorld *
      __builtin_amdgcn_rsqf(dx * dx + dy * dy + dz * dz);

  float* out_ainv = out;                     // [R, S+1]
  float* out_w    = out + kR * (kS + 1);     // [R, S]
  float* out_last = out_w + kR * kS;         // [R, 1]
  float* out_rgb  = out_last + kR;           // [R, S, 3]
  float* out_rm   = out_rgb + kR * kS * 3;   // [R, 3]

  const int base_ainv = ray * (kS + 1);
  const int base_w    = ray * kS;

  if (threadIdx.x == 0)
    __builtin_nontemporal_store(1.0f, out_ainv + base_ainv);

  const float c_base = on ? 1.0f : 0.5f;  // sigma(0) (+sigma(0) if on)

  // --- geometry helpers (closed-form in s; no cross-chunk deps) ---
  auto geom_addr = [&](int s, int wi[8]) -> unsigned long long {
    const bool  ac = (s < kS);
    const float t  = tmin + stepc * ((float)s + jit);
    const float px = fmaf(dx, t, ox);
    const float py = fmaf(dy, t, oy);
    const float pz = fmaf(dz, t, oz);
    const float fx = (px + 1.0f) * 0.5f * (float)(kG - 1);
    const float fy = (py + 1.0f) * 0.5f * (float)(kG - 1);
    const float fz = (pz + 1.0f) * 0.5f * (float)(kG - 1);
    const int ix = (int)floorf(fx);
    const int iy = (int)floorf(fy);
    const int iz = (int)floorf(fz);
    const bool reach = ac &&
        (ix >= -1) && (ix <= kG - 1) &&
        (iy >= -1) && (iy <= kG - 1) &&
        (iz >= -1) && (iz <= kG - 1);
    const int gx0 = min(max(ix, 0), kG - 1),     gx1 = min(max(ix + 1, 0), kG - 1);
    const int gy0 = min(max(iy, 0), kG - 1),     gy1 = min(max(iy + 1, 0), kG - 1);
    const int gz0 = min(max(iz, 0), kG - 1),     gz1 = min(max(iz + 1, 0), kG - 1);
    const int X0 = (gx0 >> 1) * kXS + (gx0 & 1) * 8;
    const int X1 = (gx1 >> 1) * kXS + (gx1 & 1) * 8;
    const int Y0 = (gy0 >> 1) * kYS + (gy0 & 1) * 4;
    const int Y1 = (gy1 >> 1) * kYS + (gy1 & 1) * 4;
    const int Z0 = (gz0 >> 2) * 16 + (gz0 & 3);
    const int Z1 = (gz1 >> 2) * 16 + (gz1 & 3);
    wi[0] = X0 + Y0 + Z0; wi[1] = X0 + Y0 + Z1;
    wi[2] = X0 + Y1 + Z0; wi[3] = X0 + Y1 + Z1;
    wi[4] = X1 + Y0 + Z0; wi[5] = X1 + Y0 + Z1;
    wi[6] = X1 + Y1 + Z0; wi[7] = X1 + Y1 + Z1;
    return __ballot(reach);
  };

  auto geom_w = [&](int s, float w8[8], bool& masked) {
    const float t  = tmin + stepc * ((float)s + jit);
    const float px = fmaf(dx, t, ox);
    const float py = fmaf(dy, t, oy);
    const float pz = fmaf(dz, t, oz);
    const bool inb = (px >= -1.0f) & (px <= 1.0f) &
                     (py >= -1.0f) & (py <= 1.0f) &
                     (pz >= -1.0f) & (pz <= 1.0f);
    masked = ray_out || !inb;
    const float fx = (px + 1.0f) * 0.5f * (float)(kG - 1);
    const float fy = (py + 1.0f) * 0.5f * (float)(kG - 1);
    const float fz = (pz + 1.0f) * 0.5f * (float)(kG - 1);
    const int ix = (int)floorf(fx);
    const int iy = (int)floorf(fy);
    const int iz = (int)floorf(fz);
    const float wx = fx - (float)ix;
    const float wy = fy - (float)iy;
    const float wz = fz - (float)iz;
    const float x0 = 1.0f - wx, y0 = 1.0f - wy, z0 = 1.0f - wz;
    const float wxy00 = x0 * y0, wxy01 = x0 * wy;
    const float wxy10 = wx * y0, wxy11 = wx * wy;
    const bool vx0 = ((unsigned)ix       < (unsigned)kG);
    const bool vx1 = ((unsigned)(ix + 1) < (unsigned)kG);
    const bool vy0 = ((unsigned)iy       < (unsigned)kG);
    const bool vy1 = ((unsigned)(iy + 1) < (unsigned)kG);
    const bool vz0 = ((unsigned)iz       < (unsigned)kG);
    const bool vz1 = ((unsigned)(iz + 1) < (unsigned)kG);
    w8[0] = (vx0 & vy0 & vz0) ? wxy00 * z0 : 0.0f;
    w8[1] = (vx0 & vy0 & vz1) ? wxy00 * wz : 0.0f;
    w8[2] = (vx0 & vy1 & vz0) ? wxy01 * z0 : 0.0f;
    w8[3] = (vx0 & vy1 & vz1) ? wxy01 * wz : 0.0f;
    w8[4] = (vx1 & vy0 & vz0) ? wxy10 * z0 : 0.0f;
    w8[5] = (vx1 & vy0 & vz1) ? wxy10 * wz : 0.0f;
    w8[6] = (vx1 & vy1 & vz0) ? wxy11 * z0 : 0.0f;
    w8[7] = (vx1 & vy1 & vz1) ? wxy11 * wz : 0.0f;
  };

  float incl_a[2], excl_a[2], rr_a[2], gg_a[2], bb_a[2];

  // prologue: prefetch first owned chunk (c = wv, always < kNC since wv<=7)
  unsigned cua[8], cub[8];
  bool cur_live;
  {
    int wi[8];
    const unsigned long long bal = geom_addr(wv * 64 + lane, wi);
    cur_live = (bal != 0ull);
    if (cur_live) {
      #pragma unroll
      for (int c = 0; c < 8; ++c) cua[c] = gridA[wi[c]];
      if (on) {
        #pragma unroll
        for (int c = 0; c < 8; ++c) cub[c] = gridB[wi[c]];
      }
    }
  }

  // ---- phase A: per-owned-chunk p-scan + rgb (stores scan-independent) ----
  #pragma unroll
  for (int k = 0; k < 2; ++k) {
    const int c = wv + kWPR * k;
    if (c < kNC) {
      const int s = c * 64 + lane;

      // prefetch next owned chunk before consuming current (only wv=0,k=0)
      unsigned nua[8], nub[8];
      bool nxt_live = false;
      if (c + kWPR < kNC) {
        int wi[8];
        const unsigned long long bal = geom_addr((c + kWPR) * 64 + lane, wi);
        nxt_live = (bal != 0ull);
        if (nxt_live) {
          #pragma unroll
          for (int q = 0; q < 8; ++q) nua[q] = gridA[wi[q]];
          if (on) {
            #pragma unroll
            for (int q = 0; q < 8; ++q) nub[q] = gridB[wi[q]];
          }
        }
      }

      float incl = 1.0f, excl = 1.0f;
      float rr = c_base, gg = c_base, bb = c_base;

      if (cur_live) {
        float w8[8];
        bool masked;
        geom_w(s, w8, masked);
        float dsum = 0.0f;
        float o0 = 0.0f, o1 = 0.0f, o2 = 0.0f;
        float e0 = 0.0f, e1 = 0.0f, e2 = 0.0f;
        #pragma unroll
        for (int q = 0; q < 8; ++q) {
          const float w = w8[q];
          dsum = fmaf(w, __builtin_amdgcn_cvt_f32_fp8((int)cua[q], 0), dsum);
          o0   = fmaf(w, __builtin_amdgcn_cvt_f32_fp8((int)cua[q], 1), o0);
          o1   = fmaf(w, __builtin_amdgcn_cvt_f32_fp8((int)cua[q], 2), o1);
          o2   = fmaf(w, __builtin_amdgcn_cvt_f32_fp8((int)cua[q], 3), o2);
        }
        if (on) {
          #pragma unroll
          for (int q = 0; q < 8; ++q) {
            const float w = w8[q];
            e0 = fmaf(w, __builtin_amdgcn_cvt_f32_fp8((int)cub[q], 0), e0);
            e1 = fmaf(w, __builtin_amdgcn_cvt_f32_fp8((int)cub[q], 1), e1);
            e2 = fmaf(w, __builtin_amdgcn_cvt_f32_fp8((int)cub[q], 2), e2);
          }
        }

        // p = (1+e^x)^-0.5 == exp(-softplus(x)*0.5); masked/inactive -> 1
        float p = 1.0f;
        if ((s < kS) && !masked) {
          const float expx = fexp(dsum + kActShift);
          p = fmaxf(__builtin_amdgcn_rsqf(1.0f + expx), 1e-10f);
        }

        // chunk-local inclusive product scan (proven construct)
        incl = p;
        #pragma unroll
        for (int o = 1; o < 64; o <<= 1) {
          const float n = __shfl_up(incl, o, 64);
          if (lane >= o) incl *= n;
        }
        excl = __shfl_up(incl, 1, 64);
        if (lane == 0) excl = 1.0f;

        rr = sigmoidf_(o0);
        gg = sigmoidf_(o1);
        bb = sigmoidf_(o2);
        if (on) {
          rr += sigmoidf_(e0);
          gg += sigmoidf_(e1);
          bb += sigmoidf_(e2);
        }
      }

      if (s < kS) {  // rgb has no scan dependency -> store now (coalesced)
        const int rb = (base_w + s) * 3;
        nfloat2 rg;
        rg.x = rr; rg.y = gg;
        __builtin_nontemporal_store(rg, (nfloat2*)(out_rgb + rb));
        __builtin_nontemporal_store(bb, out_rgb + rb + 2);
      }

      incl_a[k] = incl; excl_a[k] = excl;
      rr_a[k] = rr; gg_a[k] = gg; bb_a[k] = bb;

      const float prod = __shfl(incl, 63, 64);
      if (lane == 0) s_prod[c] = prod;

      cur_live = nxt_live;
      #pragma unroll
      for (int q = 0; q < 8; ++q) cua[q] = nua[q];
      if (on) {
        #pragma unroll
        for (int q = 0; q < 8; ++q) cub[q] = nub[q];
      }
    }
  }

  __syncthreads();

  float sp[kNC];
  #pragma unroll
  for (int i = 0; i < kNC; ++i) sp[i] = s_prod[i];

  // ---- phase B: chunk prefixes (uniform multiplies) + ainv/w/acc emit ----
  float accr = 0.0f, accg = 0.0f, accb = 0.0f;
  #pragma unroll
  for (int k = 0; k < 2; ++k) {
    const int c = wv + kWPR * k;
    if (c < kNC) {
      float carry = 1.0f;
      #pragma unroll
      for (int i = 0; i < kNC; ++i) carry *= (i < c) ? sp[i] : 1.0f;
      const int s = c * 64 + lane;
      const float anext = carry * incl_a[k];
      const float aprev = carry * excl_a[k];
      const float wgt   = aprev - anext;   // alpha * ainv_prev
      if (s < kS) {
        __builtin_nontemporal_store(anext, out_ainv + base_ainv + s + 1);
        __builtin_nontemporal_store(wgt, out_w + base_w + s);
        accr = fmaf(wgt, rr_a[k], accr);
        accg = fmaf(wgt, gg_a[k], accg);
        accb = fmaf(wgt, bb_a[k], accb);
      }
    }
  }

  #pragma unroll
  for (int o = 32; o > 0; o >>= 1) {
    accr += __shfl_xor(accr, o, 64);
    accg += __shfl_xor(accg, o, 64);
    accb += __shfl_xor(accb, o, 64);
  }
  if (lane == 0) {
    s_acc[wv][0] = accr;
    s_acc[wv][1] = accg;
    s_acc[wv][2] = accb;
  }
  __syncthreads();

  if (threadIdx.x == 0) {
    float sr = 0.0f, sg = 0.0f, sb = 0.0f;
    #pragma unroll
    for (int w = 0; w < kWPR; ++w) {
      sr += s_acc[w][0];
      sg += s_acc[w][1];
      sb += s_acc[w][2];
    }
    out_rm[ray * 3 + 0] = sr;
    out_rm[ray * 3 + 1] = sg;
    out_rm[ray * 3 + 2] = sb;
    float tot = 1.0f;
    #pragma unroll
    for (int i = 0; i < kNC; ++i) tot *= sp[i];
    out_last[ray] = tot;
  }
}

extern "C" void kernel_launch(void* const* d_in, const int* in_sizes, int n_in,
                              void* d_out, int out_size, void* d_ws, size_t ws_size,
                              hipStream_t stream) {
  const float* rays_o  = (const float*)d_in[0];
  const float* rays_d  = (const float*)d_in[1];
  const float* jitter  = (const float*)d_in[2];
  const int*   em      = (const int*)d_in[3];
  const float* density = (const float*)d_in[4];
  const float* off_c   = (const float*)d_in[5];
  const float* emo_c   = (const float*)d_in[6];
  float* out = (float*)d_out;

  unsigned* gridA = (unsigned*)d_ws;          // 16.4 MB
  unsigned* gridB = gridA + kGridWords;       // 16.4 MB
  (void)ws_size;

  hipLaunchKernelGGL(repack_grids, dim3((kNB * 4 + 255) / 256), dim3(256), 0,
                     stream, density, off_c, emo_c, gridA, gridB);

  hipLaunchKernelGGL(dvgo_fwd, dim3(kR), dim3(512), 0, stream,
                     rays_o, rays_d, jitter, em, gridA, gridB, out);
}

// Round 12
// 217.677 us; speedup vs baseline: 1.0996x; 1.0996x over previous
//
#include <hip/hip_runtime.h>
#include <math.h>

// DVGO volume-rendering forward, round 21 = EXACT r17 revert (best: 218.3us).
// r20 (8 waves/ray) post-mortem: VALU work DOUBLED (preamble x8 waves, dead-
// chunk waves burn setup+barrier) -> dvgo 70us. Tail-split peaks at 4 w/ray.
// Full falsification table (r9-r20): bytes/vmem-count/occupancy/latency/
// scan/instr-work/locality/tail-depth all individually null or regressive
// around r17. r17 is the composition floor of this design space: VALU 26%,
// HBM 40%, issue ~25% — nothing saturated, but both neighboring structures
// (r12 less parallel, r20 more parallel) are slower.
// Structure: 4 waves/ray (block=ray), wave w owns chunks {w,w+4,w+8};
// per-chunk shfl product-scan; chunk products through LDS, one barrier;
// uniform-multiply prefixes; interleaved coalesced stores; bricked fp8
// split grids (2x2x4 = one 64B line per 4B record corner tube).

namespace {
constexpr int   kR   = 8192;
constexpr int   kS   = 558;
constexpr int   kNC  = (kS + 63) / 64;            // 9 chunks
constexpr int   kG   = 160;
constexpr int   kG3  = kG * kG * kG;
constexpr float kNear = 0.05f;
constexpr float kFar  = 6.0f;
constexpr float kStepWorld = 0.5f * (2.0f / 160.0f);  // STEPSIZE * VOXEL_SIZE
constexpr float kActShift = -13.815509557963774f;     // log(1/(1-1e-6)-1)
constexpr float kLog2e = 1.4426950408889634f;
// brick layout: 2x2x4 voxels, 16 records x 4B = 64B = one cache line
constexpr int   kBX = 80, kBY = 80, kBZ = 40;
constexpr int   kNB = kBX * kBY * kBZ;            // 256000 bricks
constexpr int   kGridWords = kNB * 16;            // 16.4 MB per grid
constexpr int   kXS = kBY * kBZ * 16;             // x-brick stride in words
constexpr int   kYS = kBZ * 16;                   // y-brick stride in words
}

typedef unsigned int nuint4 __attribute__((ext_vector_type(4)));
typedef float        nfloat2 __attribute__((ext_vector_type(2)));
typedef float        nfloat4 __attribute__((ext_vector_type(4)));

__device__ __forceinline__ float fexp(float x) {   // e^x
  return __builtin_amdgcn_exp2f(x * kLog2e);
}
__device__ __forceinline__ float sigmoidf_(float x) {
  return __builtin_amdgcn_rcpf(1.0f + fexp(-x));
}

// ---- repack: planar 7-channel f32 -> two bricked fp8 grids (r12, proven) ----
__global__ __launch_bounds__(256) void repack_grids(
    const float* __restrict__ density,
    const float* __restrict__ off_c,
    const float* __restrict__ emo_c,
    unsigned* __restrict__ gridA,    // [kNB*16] dens|off0|off1|off2
    unsigned* __restrict__ gridB)    // [kNB*16] emo0|emo1|emo2|0
{
  const int t   = blockIdx.x * blockDim.x + threadIdx.x;
  const int bid = t >> 2;
  const int q   = t & 3;
  if (bid >= kNB) return;
  const int bz = bid % kBZ;
  const int u  = bid / kBZ;
  const int by = u % kBY;
  const int bx = u / kBY;
  const int x  = bx * 2 + (q >> 1);
  const int y  = by * 2 + (q & 1);
  const int z0 = bz * 4;
  const int vbase = (x * kG + y) * kG + z0;

  const nfloat4 d  = __builtin_nontemporal_load((const nfloat4*)(density + vbase));
  const nfloat4 f0 = __builtin_nontemporal_load((const nfloat4*)(off_c + vbase));
  const nfloat4 f1 = __builtin_nontemporal_load((const nfloat4*)(off_c + vbase + kG3));
  const nfloat4 f2 = __builtin_nontemporal_load((const nfloat4*)(off_c + vbase + 2 * kG3));
  const nfloat4 e0 = __builtin_nontemporal_load((const nfloat4*)(emo_c + vbase));
  const nfloat4 e1 = __builtin_nontemporal_load((const nfloat4*)(emo_c + vbase + kG3));
  const nfloat4 e2 = __builtin_nontemporal_load((const nfloat4*)(emo_c + vbase + 2 * kG3));

  nuint4 va, vb;
  #pragma unroll
  for (int lz = 0; lz < 4; ++lz) {
    int qa = __builtin_amdgcn_cvt_pk_fp8_f32(d[lz],  f0[lz], 0,  false);
    qa     = __builtin_amdgcn_cvt_pk_fp8_f32(f1[lz], f2[lz], qa, true);
    int qb = __builtin_amdgcn_cvt_pk_fp8_f32(e0[lz], e1[lz], 0,  false);
    qb     = __builtin_amdgcn_cvt_pk_fp8_f32(e2[lz], 0.0f,   qb, true);
    va[lz] = (unsigned)qa;
    vb[lz] = (unsigned)qb;
  }
  const size_t woff = (size_t)bid * 16 + q * 4;
  __builtin_nontemporal_store(va, (nuint4*)(gridA + woff));
  __builtin_nontemporal_store(vb, (nuint4*)(gridB + woff));
}

// ---- main: one block (4 waves) per ray; round-robin chunk ownership ----
__global__ __launch_bounds__(256) void dvgo_fwd(
    const float* __restrict__ rays_o,
    const float* __restrict__ rays_d,
    const float* __restrict__ jitter,
    const int*   __restrict__ em_modes,
    const unsigned* __restrict__ gridA,
    const unsigned* __restrict__ gridB,
    float* __restrict__ out)
{
  const int ray  = blockIdx.x;
  const int wv   = (threadIdx.x >> 6) & 3;
  const int lane = threadIdx.x & 63;

  __shared__ float s_prod[kNC];
  __shared__ float s_acc[4][3];

  const float ox = rays_o[ray * 3 + 0];
  const float oy = rays_o[ray * 3 + 1];
  const float oz = rays_o[ray * 3 + 2];
  const float dx = rays_d[ray * 3 + 0];
  const float dy = rays_d[ray * 3 + 1];
  const float dz = rays_d[ray * 3 + 2];
  const float jit = jitter[ray];
  const bool  on  = (em_modes[ray] == 1);

  const float vx = (dx == 0.0f) ? 1e-6f : dx;
  const float vy = (dy == 0.0f) ? 1e-6f : dy;
  const float vz = (dz == 0.0f) ? 1e-6f : dz;
  const float ivx = __builtin_amdgcn_rcpf(vx);
  const float ivy = __builtin_amdgcn_rcpf(vy);
  const float ivz = __builtin_amdgcn_rcpf(vz);
  const float rax = ( 1.0f - ox) * ivx, rbx = (-1.0f - ox) * ivx;
  const float ray_a = ( 1.0f - oy) * ivy, rby = (-1.0f - oy) * ivy;
  const float raz = ( 1.0f - oz) * ivz, rbz = (-1.0f - oz) * ivz;
  float tmin = fmaxf(fmaxf(fminf(rax, rbx), fminf(ray_a, rby)), fminf(raz, rbz));
  float tmax = fminf(fminf(fmaxf(rax, rbx), fmaxf(ray_a, rby)), fmaxf(raz, rbz));
  tmin = fminf(fmaxf(tmin, kNear), kFar);
  tmax = fminf(fmaxf(tmax, kNear), kFar);
  const bool  ray_out = (tmax <= tmin);
  const float stepc = kStepWorld *
      __builtin_amdgcn_rsqf(dx * dx + dy * dy + dz * dz);

  float* out_ainv = out;                     // [R, S+1]
  float* out_w    = out + kR * (kS + 1);     // [R, S]
  float* out_last = out_w + kR * kS;         // [R, 1]
  float* out_rgb  = out_last + kR;           // [R, S, 3]
  float* out_rm   = out_rgb + kR * kS * 3;   // [R, 3]

  const int base_ainv = ray * (kS + 1);
  const int base_w    = ray * kS;

  if (threadIdx.x == 0)
    __builtin_nontemporal_store(1.0f, out_ainv + base_ainv);

  const float c_base = on ? 1.0f : 0.5f;  // sigma(0) (+sigma(0) if on)

  // --- geometry helpers (closed-form in s; no cross-chunk deps) ---
  auto geom_addr = [&](int s, int wi[8]) -> unsigned long long {
    const bool  ac = (s < kS);
    const float t  = tmin + stepc * ((float)s + jit);
    const float px = fmaf(dx, t, ox);
    const float py = fmaf(dy, t, oy);
    const float pz = fmaf(dz, t, oz);
    const float fx = (px + 1.0f) * 0.5f * (float)(kG - 1);
    const float fy = (py + 1.0f) * 0.5f * (float)(kG - 1);
    const float fz = (pz + 1.0f) * 0.5f * (float)(kG - 1);
    const int ix = (int)floorf(fx);
    const int iy = (int)floorf(fy);
    const int iz = (int)floorf(fz);
    const bool reach = ac &&
        (ix >= -1) && (ix <= kG - 1) &&
        (iy >= -1) && (iy <= kG - 1) &&
        (iz >= -1) && (iz <= kG - 1);
    const int gx0 = min(max(ix, 0), kG - 1),     gx1 = min(max(ix + 1, 0), kG - 1);
    const int gy0 = min(max(iy, 0), kG - 1),     gy1 = min(max(iy + 1, 0), kG - 1);
    const int gz0 = min(max(iz, 0), kG - 1),     gz1 = min(max(iz + 1, 0), kG - 1);
    const int X0 = (gx0 >> 1) * kXS + (gx0 & 1) * 8;
    const int X1 = (gx1 >> 1) * kXS + (gx1 & 1) * 8;
    const int Y0 = (gy0 >> 1) * kYS + (gy0 & 1) * 4;
    const int Y1 = (gy1 >> 1) * kYS + (gy1 & 1) * 4;
    const int Z0 = (gz0 >> 2) * 16 + (gz0 & 3);
    const int Z1 = (gz1 >> 2) * 16 + (gz1 & 3);
    wi[0] = X0 + Y0 + Z0; wi[1] = X0 + Y0 + Z1;
    wi[2] = X0 + Y1 + Z0; wi[3] = X0 + Y1 + Z1;
    wi[4] = X1 + Y0 + Z0; wi[5] = X1 + Y0 + Z1;
    wi[6] = X1 + Y1 + Z0; wi[7] = X1 + Y1 + Z1;
    return __ballot(reach);
  };

  auto geom_w = [&](int s, float w8[8], bool& masked) {
    const float t  = tmin + stepc * ((float)s + jit);
    const float px = fmaf(dx, t, ox);
    const float py = fmaf(dy, t, oy);
    const float pz = fmaf(dz, t, oz);
    const bool inb = (px >= -1.0f) & (px <= 1.0f) &
                     (py >= -1.0f) & (py <= 1.0f) &
                     (pz >= -1.0f) & (pz <= 1.0f);
    masked = ray_out || !inb;
    const float fx = (px + 1.0f) * 0.5f * (float)(kG - 1);
    const float fy = (py + 1.0f) * 0.5f * (float)(kG - 1);
    const float fz = (pz + 1.0f) * 0.5f * (float)(kG - 1);
    const int ix = (int)floorf(fx);
    const int iy = (int)floorf(fy);
    const int iz = (int)floorf(fz);
    const float wx = fx - (float)ix;
    const float wy = fy - (float)iy;
    const float wz = fz - (float)iz;
    const float x0 = 1.0f - wx, y0 = 1.0f - wy, z0 = 1.0f - wz;
    const float wxy00 = x0 * y0, wxy01 = x0 * wy;
    const float wxy10 = wx * y0, wxy11 = wx * wy;
    const bool vx0 = ((unsigned)ix       < (unsigned)kG);
    const bool vx1 = ((unsigned)(ix + 1) < (unsigned)kG);
    const bool vy0 = ((unsigned)iy       < (unsigned)kG);
    const bool vy1 = ((unsigned)(iy + 1) < (unsigned)kG);
    const bool vz0 = ((unsigned)iz       < (unsigned)kG);
    const bool vz1 = ((unsigned)(iz + 1) < (unsigned)kG);
    w8[0] = (vx0 & vy0 & vz0) ? wxy00 * z0 : 0.0f;
    w8[1] = (vx0 & vy0 & vz1) ? wxy00 * wz : 0.0f;
    w8[2] = (vx0 & vy1 & vz0) ? wxy01 * z0 : 0.0f;
    w8[3] = (vx0 & vy1 & vz1) ? wxy01 * wz : 0.0f;
    w8[4] = (vx1 & vy0 & vz0) ? wxy10 * z0 : 0.0f;
    w8[5] = (vx1 & vy0 & vz1) ? wxy10 * wz : 0.0f;
    w8[6] = (vx1 & vy1 & vz0) ? wxy11 * z0 : 0.0f;
    w8[7] = (vx1 & vy1 & vz1) ? wxy11 * wz : 0.0f;
  };

  float incl_a[3], excl_a[3], rr_a[3], gg_a[3], bb_a[3];

  // prologue: prefetch first owned chunk (c = wv, always < kNC)
  unsigned cua[8], cub[8];
  bool cur_live;
  {
    int wi[8];
    const unsigned long long bal = geom_addr(wv * 64 + lane, wi);
    cur_live = (bal != 0ull);
    if (cur_live) {
      #pragma unroll
      for (int c = 0; c < 8; ++c) cua[c] = gridA[wi[c]];
      if (on) {
        #pragma unroll
        for (int c = 0; c < 8; ++c) cub[c] = gridB[wi[c]];
      }
    }
  }

  // ---- phase A: per-owned-chunk p-scan + rgb (stores scan-independent) ----
  #pragma unroll
  for (int k = 0; k < 3; ++k) {
    const int c = wv + 4 * k;
    if (c < kNC) {
      const int s = c * 64 + lane;

      // prefetch next owned chunk before consuming current
      unsigned nua[8], nub[8];
      bool nxt_live = false;
      if (c + 4 < kNC) {
        int wi[8];
        const unsigned long long bal = geom_addr((c + 4) * 64 + lane, wi);
        nxt_live = (bal != 0ull);
        if (nxt_live) {
          #pragma unroll
          for (int q = 0; q < 8; ++q) nua[q] = gridA[wi[q]];
          if (on) {
            #pragma unroll
            for (int q = 0; q < 8; ++q) nub[q] = gridB[wi[q]];
          }
        }
      }

      float incl = 1.0f, excl = 1.0f;
      float rr = c_base, gg = c_base, bb = c_base;

      if (cur_live) {
        float w8[8];
        bool masked;
        geom_w(s, w8, masked);
        float dsum = 0.0f;
        float o0 = 0.0f, o1 = 0.0f, o2 = 0.0f;
        float e0 = 0.0f, e1 = 0.0f, e2 = 0.0f;
        #pragma unroll
        for (int q = 0; q < 8; ++q) {
          const float w = w8[q];
          dsum = fmaf(w, __builtin_amdgcn_cvt_f32_fp8((int)cua[q], 0), dsum);
          o0   = fmaf(w, __builtin_amdgcn_cvt_f32_fp8((int)cua[q], 1), o0);
          o1   = fmaf(w, __builtin_amdgcn_cvt_f32_fp8((int)cua[q], 2), o1);
          o2   = fmaf(w, __builtin_amdgcn_cvt_f32_fp8((int)cua[q], 3), o2);
        }
        if (on) {
          #pragma unroll
          for (int q = 0; q < 8; ++q) {
            const float w = w8[q];
            e0 = fmaf(w, __builtin_amdgcn_cvt_f32_fp8((int)cub[q], 0), e0);
            e1 = fmaf(w, __builtin_amdgcn_cvt_f32_fp8((int)cub[q], 1), e1);
            e2 = fmaf(w, __builtin_amdgcn_cvt_f32_fp8((int)cub[q], 2), e2);
          }
        }

        // p = (1+e^x)^-0.5 == exp(-softplus(x)*0.5); masked/inactive -> 1
        float p = 1.0f;
        if ((s < kS) && !masked) {
          const float expx = fexp(dsum + kActShift);
          p = fmaxf(__builtin_amdgcn_rsqf(1.0f + expx), 1e-10f);
        }

        // chunk-local inclusive product scan (proven construct)
        incl = p;
        #pragma unroll
        for (int o = 1; o < 64; o <<= 1) {
          const float n = __shfl_up(incl, o, 64);
          if (lane >= o) incl *= n;
        }
        excl = __shfl_up(incl, 1, 64);
        if (lane == 0) excl = 1.0f;

        rr = sigmoidf_(o0);
        gg = sigmoidf_(o1);
        bb = sigmoidf_(o2);
        if (on) {
          rr += sigmoidf_(e0);
          gg += sigmoidf_(e1);
          bb += sigmoidf_(e2);
        }
      }

      if (s < kS) {  // rgb has no scan dependency -> store now (coalesced)
        const int rb = (base_w + s) * 3;
        nfloat2 rg;
        rg.x = rr; rg.y = gg;
        __builtin_nontemporal_store(rg, (nfloat2*)(out_rgb + rb));
        __builtin_nontemporal_store(bb, out_rgb + rb + 2);
      }

      incl_a[k] = incl; excl_a[k] = excl;
      rr_a[k] = rr; gg_a[k] = gg; bb_a[k] = bb;

      const float prod = __shfl(incl, 63, 64);
      if (lane == 0) s_prod[c] = prod;

      cur_live = nxt_live;
      #pragma unroll
      for (int q = 0; q < 8; ++q) cua[q] = nua[q];
      if (on) {
        #pragma unroll
        for (int q = 0; q < 8; ++q) cub[q] = nub[q];
      }
    }
  }

  __syncthreads();

  float sp[kNC];
  #pragma unroll
  for (int i = 0; i < kNC; ++i) sp[i] = s_prod[i];

  // ---- phase B: chunk prefixes (uniform multiplies) + ainv/w/acc emit ----
  float accr = 0.0f, accg = 0.0f, accb = 0.0f;
  #pragma unroll
  for (int k = 0; k < 3; ++k) {
    const int c = wv + 4 * k;
    if (c < kNC) {
      float carry = 1.0f;
      #pragma unroll
      for (int i = 0; i < kNC; ++i) carry *= (i < c) ? sp[i] : 1.0f;
      const int s = c * 64 + lane;
      const float anext = carry * incl_a[k];
      const float aprev = carry * excl_a[k];
      const float wgt   = aprev - anext;   // alpha * ainv_prev
      if (s < kS) {
        __builtin_nontemporal_store(anext, out_ainv + base_ainv + s + 1);
        __builtin_nontemporal_store(wgt, out_w + base_w + s);
        accr = fmaf(wgt, rr_a[k], accr);
        accg = fmaf(wgt, gg_a[k], accg);
        accb = fmaf(wgt, bb_a[k], accb);
      }
    }
  }

  #pragma unroll
  for (int o = 32; o > 0; o >>= 1) {
    accr += __shfl_xor(accr, o, 64);
    accg += __shfl_xor(accg, o, 64);
    accb += __shfl_xor(accb, o, 64);
  }
  if (lane == 0) {
    s_acc[wv][0] = accr;
    s_acc[wv][1] = accg;
    s_acc[wv][2] = accb;
  }
  __syncthreads();

  if (threadIdx.x == 0) {
    out_rm[ray * 3 + 0] = s_acc[0][0] + s_acc[1][0] + s_acc[2][0] + s_acc[3][0];
    out_rm[ray * 3 + 1] = s_acc[0][1] + s_acc[1][1] + s_acc[2][1] + s_acc[3][1];
    out_rm[ray * 3 + 2] = s_acc[0][2] + s_acc[1][2] + s_acc[2][2] + s_acc[3][2];
    float tot = 1.0f;
    #pragma unroll
    for (int i = 0; i < kNC; ++i) tot *= sp[i];
    out_last[ray] = tot;
  }
}

extern "C" void kernel_launch(void* const* d_in, const int* in_sizes, int n_in,
                              void* d_out, int out_size, void* d_ws, size_t ws_size,
                              hipStream_t stream) {
  const float* rays_o  = (const float*)d_in[0];
  const float* rays_d  = (const float*)d_in[1];
  const float* jitter  = (const float*)d_in[2];
  const int*   em      = (const int*)d_in[3];
  const float* density = (const float*)d_in[4];
  const float* off_c   = (const float*)d_in[5];
  const float* emo_c   = (const float*)d_in[6];
  float* out = (float*)d_out;

  unsigned* gridA = (unsigned*)d_ws;          // 16.4 MB
  unsigned* gridB = gridA + kGridWords;       // 16.4 MB
  (void)ws_size;

  hipLaunchKernelGGL(repack_grids, dim3((kNB * 4 + 255) / 256), dim3(256), 0,
                     stream, density, off_c, emo_c, gridA, gridB);

  hipLaunchKernelGGL(dvgo_fwd, dim3(kR), dim3(256), 0, stream,
                     rays_o, rays_d, jitter, em, gridA, gridB, out);
}